// Round 12
// baseline (62.854 us; speedup 1.0000x reference)
//
#include <hip/hip_runtime.h>
#include <float.h>

#define BATCH 4

typedef _Float16 half8 __attribute__((ext_vector_type(8)));
typedef float f32x16 __attribute__((ext_vector_type(16)));
typedef float f32x2 __attribute__((ext_vector_type(2)));

// ================= MFMA path =================
// D[p,q] = |p|^2 + |q|^2 - 2 p.q  via K=13 fp16 slots (exact split):
//  A[p] = [hx,hy,hz, hx,hy,hz, ex,ey,ez, ps_h, ps_e, 1, 1, 0,0,0]
//  B[q] = [-2hx,-2hy,-2hz, -2ex,-2ey,-2ez, -2hx,-2hy,-2hz, 1, 1, qs_h, qs_e, 0,0,0]
// fp16*fp16 products exact in fp32 accumulator. Verified R7-R11 (absmax ~1e-3).
// Role-symmetric: A rows = dst (scan) points, B cols = src (owned) points.

__global__ void prep_fp16(const float* __restrict__ x1, const float* __restrict__ x2,
                          _Float16* __restrict__ pa1, _Float16* __restrict__ pb1,
                          _Float16* __restrict__ pa2, _Float16* __restrict__ pb2,
                          float* __restrict__ out, int n1, int n2, int outn) {
    const int i = blockIdx.x * blockDim.x + threadIdx.x;
    const _Float16 one = (_Float16)1.0f, zro = (_Float16)0.0f;

    #pragma unroll
    for (int which = 0; which < 2; ++which) {
        const int n = which ? n2 : n1;
        if (i >= n) continue;
        const float* xp = (which ? x2 : x1) + 3 * (size_t)i;
        _Float16* pa = (which ? pa2 : pa1) + 16 * (size_t)i;
        _Float16* pb = (which ? pb2 : pb1) + 16 * (size_t)i;

        const float x = xp[0], y = xp[1], z = xp[2];
        const _Float16 hx = (_Float16)x, hy = (_Float16)y, hz = (_Float16)z;
        const _Float16 ex = (_Float16)(x - (float)hx);
        const _Float16 ey = (_Float16)(y - (float)hy);
        const _Float16 ez = (_Float16)(z - (float)hz);
        const float ps = fmaf(x, x, fmaf(y, y, z * z));
        const _Float16 ph = (_Float16)ps;
        const _Float16 pe = (_Float16)(ps - (float)ph);
        const _Float16 tx = (_Float16)(-2.0f * (float)hx);
        const _Float16 ty = (_Float16)(-2.0f * (float)hy);
        const _Float16 tz = (_Float16)(-2.0f * (float)hz);
        const _Float16 ux = (_Float16)(-2.0f * (float)ex);
        const _Float16 uy = (_Float16)(-2.0f * (float)ey);
        const _Float16 uz = (_Float16)(-2.0f * (float)ez);

        const half8 a0 = (half8){hx, hy, hz, hx, hy, hz, ex, ey};
        const half8 a1 = (half8){ez, ph, pe, one, one, zro, zro, zro};
        const half8 b0 = (half8){tx, ty, tz, ux, uy, uz, tx, ty};
        const half8 b1 = (half8){tz, one, one, ph, pe, zro, zro, zro};

        *(half8*)(pa)     = a0;   // 16B vector stores
        *(half8*)(pa + 8) = a1;
        *(half8*)(pb)     = b0;
        *(half8*)(pb + 8) = b1;
    }
    if (i < outn) out[i] = FLT_MAX;
}

// Fold 16 fresh distances + running min into one scalar: 8 v_min3-class ops.
__device__ inline float min16_into(float r, const f32x16 d) {
    const float t0 = fminf(fminf(d[0],  d[1]),  d[2]);
    const float t1 = fminf(fminf(d[3],  d[4]),  d[5]);
    const float t2 = fminf(fminf(d[6],  d[7]),  d[8]);
    const float t3 = fminf(fminf(d[9],  d[10]), d[11]);
    const float t4 = fminf(fminf(d[12], d[13]), d[14]);
    const float u0 = fminf(fminf(t0, t1), t2);
    const float u1 = fminf(fminf(t3, t4), d[15]);
    return fminf(fminf(r, u0), u1);
}

// Block: 4 waves x IT=2 src-tiles of 32 cols = 256 src points per block.
// Sweeps a j-segment (N/NJ dst points) in LDS stages of 256 = 8 A-tiles,
// DOUBLE-BUFFERED (R9 schedule, race-checked): stage s+1's global loads are
// issued BEFORE stage s's compute; the LDS write of s+1 goes to the other
// buffer after compute; ONE barrier per stage. Global-load latency hides
// under the 16-MFMA + min-tree compute phase (T14).
// src points are the MFMA *B* operand -> every lane's 16 D elements belong
// to its own src point (col = lane&31); min over the scan dim is in-register.
// NOTE: plain __launch_bounds__(256) — R5/R9: any min-waves arg register-
// starves this kernel family and spills f32x16 temps to scratch.
// Layouts (verified R8/R10/R11):
//  A/B frag: row/col = lane&31, k-half = lane>>5 (8 contiguous f16 = 16B)
//  D: col = lane&31 (src i), row = (e&3)+8*(e>>2)+4*(lane>>5) (dst j)
template<int NJ>
__global__ __launch_bounds__(256) void chamfer_mfma32(
        const _Float16* __restrict__ pa1, const _Float16* __restrict__ pb1,
        const _Float16* __restrict__ pa2, const _Float16* __restrict__ pb2,
        float* __restrict__ out, int N) {
    constexpr int IT = 2;
    __shared__ uint4 sA[2][512];   // 2 x 8 KiB

    const int tid  = threadIdx.x;
    const int lane = tid & 63;
    const int w    = tid >> 6;

    int bid = blockIdx.x;
    const int RB      = N / 256;
    const int per_dir = BATCH * RB * NJ;
    const int dir = bid / per_dir;   bid %= per_dir;
    const int b   = bid / (RB * NJ); bid %= (RB * NJ);
    const int cb  = bid / NJ;        // src col-block
    const int js  = bid % NJ;        // dst segment

    // dir0: src=set1 (held B-form), scan dst=set2 (staged A-form)
    const _Float16* pstage = dir ? pa1 : pa2;
    const _Float16* pheld  = dir ? pb2 : pb1;
    float* outd = out + (size_t)dir * BATCH * N + (size_t)b * N;

    const int jseg   = N / NJ;
    const int stages = jseg / 256;
    const uint4* gs  = (const uint4*)pstage;
    const int t = tid >> 5, col = tid & 31;
    const size_t qbase = (size_t)(b * N + js * jseg) * 2;

    // prologue: issue stage-0 loads first (longest to hide under bf gather)
    uint4 v0 = gs[qbase + (size_t)tid * 2];
    uint4 v1 = gs[qbase + (size_t)tid * 2 + 1];

    // Held src B-fragments: 16B per lane.
    const int colbase = cb * 256 + w * 64;
    const uint4* gh = (const uint4*)pheld;
    half8 bf[IT];
    #pragma unroll
    for (int it = 0; it < IT; ++it) {
        const int c = colbase + it * 32 + (lane & 31);
        bf[it] = __builtin_bit_cast(half8, gh[(size_t)(b * N + c) * 2 + (lane >> 5)]);
    }

    float rmin[IT];
    #pragma unroll
    for (int it = 0; it < IT; ++it) rmin[it] = FLT_MAX;

    f32x16 cz;
    #pragma unroll
    for (int e = 0; e < 16; ++e) cz[e] = 0.0f;

    // write stage 0 into buf 0
    sA[0][t * 64 + col]      = v0;
    sA[0][t * 64 + 32 + col] = v1;
    __syncthreads();

    for (int s = 0; s < stages; ++s) {
        const int cur = s & 1;
        if (s + 1 < stages) {               // issue next stage's loads EARLY
            const size_t q = qbase + ((size_t)(s + 1) * 256 + tid) * 2;
            v0 = gs[q]; v1 = gs[q + 1];
        }

        #pragma unroll
        for (int p = 0; p < 8; ++p) {
            const half8 a = __builtin_bit_cast(half8, sA[cur][p * 64 + lane]);
            #pragma unroll
            for (int it = 0; it < IT; ++it) {
                const f32x16 d = __builtin_amdgcn_mfma_f32_32x32x16_f16(a, bf[it], cz, 0, 0, 0);
                rmin[it] = min16_into(rmin[it], d);
            }
        }

        if (s + 1 < stages) {               // write other buffer after compute;
            sA[cur ^ 1][t * 64 + col]      = v0;   // cur^1 was consumed in s-1,
            sA[cur ^ 1][t * 64 + 32 + col] = v1;   // all waves passed last barrier
        }
        __syncthreads();                    // one barrier per stage
    }

    // epilogue: combine k-halves (lane L and L^32 hold complementary rows)
    #pragma unroll
    for (int it = 0; it < IT; ++it) {
        float v = fminf(rmin[it], __shfl_xor(rmin[it], 32, 64));
        v = fmaxf(v, 0.0f);              // >=0 keeps int-punned min ordering
        if (lane < 32)
            atomicMin((int*)&outd[colbase + it * 32 + lane], __float_as_int(v));
    }
}

// ================= fallback: R6 pk-fma path =================
__global__ void chamfer_prep(const float* __restrict__ xyz1,
                             const float* __restrict__ xyz2,
                             float4* __restrict__ pk1,
                             float4* __restrict__ pk2,
                             float* __restrict__ out,
                             int n1, int n2, int out_n) {
    int i = blockIdx.x * blockDim.x + threadIdx.x;
    if (i < n1) {
        float x = xyz1[3 * (size_t)i], y = xyz1[3 * (size_t)i + 1], z = xyz1[3 * (size_t)i + 2];
        pk1[i] = make_float4(-2.f * x, -2.f * y, -2.f * z, fmaf(x, x, fmaf(y, y, z * z)));
    }
    if (i < n2) {
        float x = xyz2[3 * (size_t)i], y = xyz2[3 * (size_t)i + 1], z = xyz2[3 * (size_t)i + 2];
        pk2[i] = make_float4(-2.f * x, -2.f * y, -2.f * z, fmaf(x, x, fmaf(y, y, z * z)));
    }
    if (i < out_n) out[i] = FLT_MAX;
}

template<int TPB, int CHUNK, int P>
__global__ __launch_bounds__(TPB) void chamfer_fused(
        const float* __restrict__ xyz1, const float* __restrict__ xyz2,
        const float4* __restrict__ pk1, const float4* __restrict__ pk2,
        float* __restrict__ out, int N, int M, int blocks_dir0) {
    __shared__ float4 s[CHUNK];
    int bid = blockIdx.x;
    const int dir = (bid >= blocks_dir0) ? 1 : 0;
    if (dir) bid -= blocks_dir0;
    const int Nsrc = dir ? M : N;
    const int Mdst = dir ? N : M;
    const float* src   = dir ? xyz2 : xyz1;
    const float4* dstp = dir ? pk1  : pk2;
    float* outd        = dir ? (out + (size_t)BATCH * N) : out;
    const int YT = Nsrc / (TPB * P);
    const int Z  = Mdst / CHUNK;
    const int b  = bid / (YT * Z);
    const int r  = bid % (YT * Z);
    const int yt = r / Z;
    const int z  = r % Z;
    const float4* dchunk = dstp + (size_t)b * Mdst + (size_t)z * CHUNK;
    for (int t = threadIdx.x; t < CHUNK / 2; t += TPB) {
        const float4 q0 = dchunk[2 * t];
        const float4 q1 = dchunk[2 * t + 1];
        s[2 * t]     = make_float4(q0.x, q1.x, q0.y, q1.y);
        s[2 * t + 1] = make_float4(q0.z, q1.z, q0.w, q1.w);
    }
    const int i0 = yt * (TPB * P) + threadIdx.x;
    f32x2 px[P], py[P], pz[P];
    float psq[P], m[P];
    #pragma unroll
    for (int k = 0; k < P; ++k) {
        const int i = i0 + k * TPB;
        const float* p = src + ((size_t)b * Nsrc + i) * 3;
        const float x = p[0], y = p[1], zc = p[2];
        px[k] = (f32x2){x, x}; py[k] = (f32x2){y, y}; pz[k] = (f32x2){zc, zc};
        psq[k] = fmaf(x, x, fmaf(y, y, zc * zc));
        m[k] = FLT_MAX;
    }
    __syncthreads();
    #pragma unroll 8
    for (int jj = 0; jj < CHUNK / 2; ++jj) {
        const float4 A = s[2 * jj];
        const float4 B = s[2 * jj + 1];
        const f32x2 xq = (f32x2){A.x, A.y};
        const f32x2 yq = (f32x2){A.z, A.w};
        const f32x2 zq = (f32x2){B.x, B.y};
        const f32x2 wq = (f32x2){B.z, B.w};
        #pragma unroll
        for (int k = 0; k < P; ++k) {
            const f32x2 e = __builtin_elementwise_fma(xq, px[k],
                             __builtin_elementwise_fma(yq, py[k],
                              __builtin_elementwise_fma(zq, pz[k], wq)));
            m[k] = fminf(fminf(m[k], e.x), e.y);
        }
    }
    #pragma unroll
    for (int k = 0; k < P; ++k) {
        const int i = i0 + k * TPB;
        const float d = fmaxf(psq[k] + m[k], 0.0f);
        atomicMin((int*)&outd[(size_t)b * Nsrc + i], __float_as_int(d));
    }
}

extern "C" void kernel_launch(void* const* d_in, const int* in_sizes, int n_in,
                              void* d_out, int out_size, void* d_ws, size_t ws_size,
                              hipStream_t stream) {
    const float* xyz1 = (const float*)d_in[0];
    const float* xyz2 = (const float*)d_in[1];
    float* out = (float*)d_out;

    const int N = in_sizes[0] / (BATCH * 3);  // 8192
    const int M = in_sizes[1] / (BATCH * 3);  // 8192
    const int n1 = BATCH * N, n2 = BATCH * M;

    constexpr int TPB = 256;
    constexpr int NJ = 8;

    const size_t need16 = ((size_t)n1 + (size_t)n2) * 64;  // A+B fp16 forms
    const bool mfma_ok = (N == M) && (N % (NJ * 256) == 0) && (ws_size >= need16);

    if (mfma_ok) {
        _Float16* pa1 = (_Float16*)d_ws;
        _Float16* pb1 = pa1 + (size_t)n1 * 16;
        _Float16* pa2 = pb1 + (size_t)n1 * 16;
        _Float16* pb2 = pa2 + (size_t)n2 * 16;
        int prep_n = out_size > n1 ? out_size : n1;
        if (n2 > prep_n) prep_n = n2;
        prep_fp16<<<(prep_n + TPB - 1) / TPB, TPB, 0, stream>>>(
            xyz1, xyz2, pa1, pb1, pa2, pb2, out, n1, n2, out_size);

        const int grid = 2 * BATCH * (N / 256) * NJ;   // 2048
        chamfer_mfma32<NJ><<<grid, TPB, 0, stream>>>(pa1, pb1, pa2, pb2, out, N);
        return;
    }

    // fallback: R6 pk-fma path
    constexpr int CHUNK = 128;
    constexpr int P = 8;
    const size_t need = ((size_t)n1 + (size_t)n2) * sizeof(float4);
    if (ws_size >= need && (N % (TPB * P) == 0) && (M % (TPB * P) == 0) &&
        (N % CHUNK == 0) && (M % CHUNK == 0)) {
        float4* pk1 = (float4*)d_ws;
        float4* pk2 = pk1 + n1;
        int prep_n = out_size > n1 ? out_size : n1;
        if (n2 > prep_n) prep_n = n2;
        chamfer_prep<<<(prep_n + TPB - 1) / TPB, TPB, 0, stream>>>(
            xyz1, xyz2, pk1, pk2, out, n1, n2, out_size);
        const int blocks_dir0 = BATCH * (N / (TPB * P)) * (M / CHUNK);
        const int blocks_dir1 = BATCH * (M / (TPB * P)) * (N / CHUNK);
        chamfer_fused<TPB, CHUNK, P><<<blocks_dir0 + blocks_dir1, TPB, 0, stream>>>(
            xyz1, xyz2, pk1, pk2, out, N, M, blocks_dir0);
    }
}

// Round 13
// 38.349 us; speedup vs baseline: 1.6390x; 1.6390x over previous
//
#include <hip/hip_runtime.h>
#include <float.h>

#define BATCH 4

typedef _Float16 half8 __attribute__((ext_vector_type(8)));
typedef float f32x16 __attribute__((ext_vector_type(16)));
typedef float f32x2 __attribute__((ext_vector_type(2)));

// ================= MFMA path =================
// D[p,q] = |p|^2 + |q|^2 - 2 p.q  via K=13 fp16 slots (exact split):
//  A[p] = [hx,hy,hz, hx,hy,hz, ex,ey,ez, ps_h, ps_e, 1, 1, 0,0,0]
//  B[q] = [-2hx,-2hy,-2hz, -2ex,-2ey,-2ez, -2hx,-2hy,-2hz, 1, 1, qs_h, qs_e, 0,0,0]
// fp16*fp16 products exact in fp32 accumulator. Verified R7-R12 (absmax ~1e-3).
// A rows = dst (scan) points, B cols = src (owned) points.

__global__ void prep_fp16(const float* __restrict__ x1, const float* __restrict__ x2,
                          _Float16* __restrict__ pa1, _Float16* __restrict__ pb1,
                          _Float16* __restrict__ pa2, _Float16* __restrict__ pb2,
                          float* __restrict__ out, int n1, int n2, int outn) {
    const int i = blockIdx.x * blockDim.x + threadIdx.x;
    const _Float16 one = (_Float16)1.0f, zro = (_Float16)0.0f;

    #pragma unroll
    for (int which = 0; which < 2; ++which) {
        const int n = which ? n2 : n1;
        if (i >= n) continue;
        const float* xp = (which ? x2 : x1) + 3 * (size_t)i;
        _Float16* pa = (which ? pa2 : pa1) + 16 * (size_t)i;
        _Float16* pb = (which ? pb2 : pb1) + 16 * (size_t)i;

        const float x = xp[0], y = xp[1], z = xp[2];
        const _Float16 hx = (_Float16)x, hy = (_Float16)y, hz = (_Float16)z;
        const _Float16 ex = (_Float16)(x - (float)hx);
        const _Float16 ey = (_Float16)(y - (float)hy);
        const _Float16 ez = (_Float16)(z - (float)hz);
        const float ps = fmaf(x, x, fmaf(y, y, z * z));
        const _Float16 ph = (_Float16)ps;
        const _Float16 pe = (_Float16)(ps - (float)ph);
        const _Float16 tx = (_Float16)(-2.0f * (float)hx);
        const _Float16 ty = (_Float16)(-2.0f * (float)hy);
        const _Float16 tz = (_Float16)(-2.0f * (float)hz);
        const _Float16 ux = (_Float16)(-2.0f * (float)ex);
        const _Float16 uy = (_Float16)(-2.0f * (float)ey);
        const _Float16 uz = (_Float16)(-2.0f * (float)ez);

        const half8 a0 = (half8){hx, hy, hz, hx, hy, hz, ex, ey};
        const half8 a1 = (half8){ez, ph, pe, one, one, zro, zro, zro};
        const half8 b0 = (half8){tx, ty, tz, ux, uy, uz, tx, ty};
        const half8 b1 = (half8){tz, one, one, ph, pe, zro, zro, zro};

        *(half8*)(pa)     = a0;   // 16B vector stores
        *(half8*)(pa + 8) = a1;
        *(half8*)(pb)     = b0;
        *(half8*)(pb + 8) = b1;
    }
    if (i < outn) out[i] = FLT_MAX;
}

// Fold 16 fresh distances + running min into one scalar: 8 v_min3-class ops.
__device__ inline float min16_into(float r, const f32x16 d) {
    const float t0 = fminf(fminf(d[0],  d[1]),  d[2]);
    const float t1 = fminf(fminf(d[3],  d[4]),  d[5]);
    const float t2 = fminf(fminf(d[6],  d[7]),  d[8]);
    const float t3 = fminf(fminf(d[9],  d[10]), d[11]);
    const float t4 = fminf(fminf(d[12], d[13]), d[14]);
    const float u0 = fminf(fminf(t0, t1), t2);
    const float u1 = fminf(fminf(t3, t4), d[15]);
    return fminf(fminf(r, u0), u1);
}

// LDS-FREE, BARRIER-FREE variant (R13). The packed dst array (4MB/dir) is
// L2-resident; staging it through LDS (R11/R12) bought nothing and cost
// barriers + VGPR-hungry pipelining (R12: VGPR 148 -> 2 waves/SIMD -> 57us).
// Each wave streams its j-segment's A-fragments directly from global:
// lane reads point (tile*32 + (lane&31)), uint4-half (lane>>5) — the exact
// element R11's LDS slot sA[t*64+lane] held, so the MFMA sees identical
// operands. 2KB contiguous per wave-load, fully coalesced, L2-served.
// #pragma unroll 2 caps in-flight (a,d) tuples: VGPR must stay < 128 cliff.
// NOTE: plain __launch_bounds__(256) — R5/R9: min-waves args spill f32x16.
// Layouts (verified R8/R10/R11):
//  A/B frag: row/col = lane&31, k-half = lane>>5 (8 contiguous f16 = 16B)
//  D: col = lane&31 (src i), row = (e&3)+8*(e>>2)+4*(lane>>5) (dst j)
template<int NJ>
__global__ __launch_bounds__(256) void chamfer_mfma32(
        const _Float16* __restrict__ pa1, const _Float16* __restrict__ pb1,
        const _Float16* __restrict__ pa2, const _Float16* __restrict__ pb2,
        float* __restrict__ out, int N) {
    constexpr int IT = 2;

    const int tid  = threadIdx.x;
    const int lane = tid & 63;
    const int w    = tid >> 6;

    int bid = blockIdx.x;
    const int RB      = N / 256;
    const int per_dir = BATCH * RB * NJ;
    const int dir = bid / per_dir;   bid %= per_dir;
    const int b   = bid / (RB * NJ); bid %= (RB * NJ);
    const int cb  = bid / NJ;        // src col-block
    const int js  = bid % NJ;        // dst segment

    // dir0: src=set1 (held B-form), scan dst=set2 (streamed A-form)
    const _Float16* pstream = dir ? pa1 : pa2;
    const _Float16* pheld   = dir ? pb2 : pb1;
    float* outd = out + (size_t)dir * BATCH * N + (size_t)b * N;

    // Held src B-fragments: 16B per lane.
    const int colbase = cb * 256 + w * 64;
    const uint4* gh = (const uint4*)pheld;
    half8 bf[IT];
    #pragma unroll
    for (int it = 0; it < IT; ++it) {
        const int c = colbase + it * 32 + (lane & 31);
        bf[it] = __builtin_bit_cast(half8, gh[(size_t)(b * N + c) * 2 + (lane >> 5)]);
    }

    float rmin[IT];
    #pragma unroll
    for (int it = 0; it < IT; ++it) rmin[it] = FLT_MAX;

    f32x16 cz;
    #pragma unroll
    for (int e = 0; e < 16; ++e) cz[e] = 0.0f;

    const int jseg   = N / NJ;
    const int ntiles = jseg / 32;
    const uint4* gs  = (const uint4*)pstream;
    // lane's fixed A-fragment address within a tile (uint4 units):
    const size_t abase = (size_t)(b * N + js * jseg) * 2
                       + (size_t)(lane & 31) * 2 + (lane >> 5);

    #pragma unroll 2
    for (int tt = 0; tt < ntiles; ++tt) {
        const half8 a = __builtin_bit_cast(half8, gs[abase + (size_t)tt * 64]);
        #pragma unroll
        for (int it = 0; it < IT; ++it) {
            const f32x16 d = __builtin_amdgcn_mfma_f32_32x32x16_f16(a, bf[it], cz, 0, 0, 0);
            rmin[it] = min16_into(rmin[it], d);
        }
    }

    // epilogue: combine k-halves (lane L and L^32 hold complementary rows)
    #pragma unroll
    for (int it = 0; it < IT; ++it) {
        float v = fminf(rmin[it], __shfl_xor(rmin[it], 32, 64));
        v = fmaxf(v, 0.0f);              // >=0 keeps int-punned min ordering
        if (lane < 32)
            atomicMin((int*)&outd[colbase + it * 32 + lane], __float_as_int(v));
    }
}

// ================= fallback: R6 pk-fma path =================
__global__ void chamfer_prep(const float* __restrict__ xyz1,
                             const float* __restrict__ xyz2,
                             float4* __restrict__ pk1,
                             float4* __restrict__ pk2,
                             float* __restrict__ out,
                             int n1, int n2, int out_n) {
    int i = blockIdx.x * blockDim.x + threadIdx.x;
    if (i < n1) {
        float x = xyz1[3 * (size_t)i], y = xyz1[3 * (size_t)i + 1], z = xyz1[3 * (size_t)i + 2];
        pk1[i] = make_float4(-2.f * x, -2.f * y, -2.f * z, fmaf(x, x, fmaf(y, y, z * z)));
    }
    if (i < n2) {
        float x = xyz2[3 * (size_t)i], y = xyz2[3 * (size_t)i + 1], z = xyz2[3 * (size_t)i + 2];
        pk2[i] = make_float4(-2.f * x, -2.f * y, -2.f * z, fmaf(x, x, fmaf(y, y, z * z)));
    }
    if (i < out_n) out[i] = FLT_MAX;
}

template<int TPB, int CHUNK, int P>
__global__ __launch_bounds__(TPB) void chamfer_fused(
        const float* __restrict__ xyz1, const float* __restrict__ xyz2,
        const float4* __restrict__ pk1, const float4* __restrict__ pk2,
        float* __restrict__ out, int N, int M, int blocks_dir0) {
    __shared__ float4 s[CHUNK];
    int bid = blockIdx.x;
    const int dir = (bid >= blocks_dir0) ? 1 : 0;
    if (dir) bid -= blocks_dir0;
    const int Nsrc = dir ? M : N;
    const int Mdst = dir ? N : M;
    const float* src   = dir ? xyz2 : xyz1;
    const float4* dstp = dir ? pk1  : pk2;
    float* outd        = dir ? (out + (size_t)BATCH * N) : out;
    const int YT = Nsrc / (TPB * P);
    const int Z  = Mdst / CHUNK;
    const int b  = bid / (YT * Z);
    const int r  = bid % (YT * Z);
    const int yt = r / Z;
    const int z  = r % Z;
    const float4* dchunk = dstp + (size_t)b * Mdst + (size_t)z * CHUNK;
    for (int t = threadIdx.x; t < CHUNK / 2; t += TPB) {
        const float4 q0 = dchunk[2 * t];
        const float4 q1 = dchunk[2 * t + 1];
        s[2 * t]     = make_float4(q0.x, q1.x, q0.y, q1.y);
        s[2 * t + 1] = make_float4(q0.z, q1.z, q0.w, q1.w);
    }
    const int i0 = yt * (TPB * P) + threadIdx.x;
    f32x2 px[P], py[P], pz[P];
    float psq[P], m[P];
    #pragma unroll
    for (int k = 0; k < P; ++k) {
        const int i = i0 + k * TPB;
        const float* p = src + ((size_t)b * Nsrc + i) * 3;
        const float x = p[0], y = p[1], zc = p[2];
        px[k] = (f32x2){x, x}; py[k] = (f32x2){y, y}; pz[k] = (f32x2){zc, zc};
        psq[k] = fmaf(x, x, fmaf(y, y, zc * zc));
        m[k] = FLT_MAX;
    }
    __syncthreads();
    #pragma unroll 8
    for (int jj = 0; jj < CHUNK / 2; ++jj) {
        const float4 A = s[2 * jj];
        const float4 B = s[2 * jj + 1];
        const f32x2 xq = (f32x2){A.x, A.y};
        const f32x2 yq = (f32x2){A.z, A.w};
        const f32x2 zq = (f32x2){B.x, B.y};
        const f32x2 wq = (f32x2){B.z, B.w};
        #pragma unroll
        for (int k = 0; k < P; ++k) {
            const f32x2 e = __builtin_elementwise_fma(xq, px[k],
                             __builtin_elementwise_fma(yq, py[k],
                              __builtin_elementwise_fma(zq, pz[k], wq)));
            m[k] = fminf(fminf(m[k], e.x), e.y);
        }
    }
    #pragma unroll
    for (int k = 0; k < P; ++k) {
        const int i = i0 + k * TPB;
        const float d = fmaxf(psq[k] + m[k], 0.0f);
        atomicMin((int*)&outd[(size_t)b * Nsrc + i], __float_as_int(d));
    }
}

extern "C" void kernel_launch(void* const* d_in, const int* in_sizes, int n_in,
                              void* d_out, int out_size, void* d_ws, size_t ws_size,
                              hipStream_t stream) {
    const float* xyz1 = (const float*)d_in[0];
    const float* xyz2 = (const float*)d_in[1];
    float* out = (float*)d_out;

    const int N = in_sizes[0] / (BATCH * 3);  // 8192
    const int M = in_sizes[1] / (BATCH * 3);  // 8192
    const int n1 = BATCH * N, n2 = BATCH * M;

    constexpr int TPB = 256;
    constexpr int NJ = 8;

    const size_t need16 = ((size_t)n1 + (size_t)n2) * 64;  // A+B fp16 forms
    const bool mfma_ok = (N == M) && (N % (NJ * 256) == 0) && (ws_size >= need16);

    if (mfma_ok) {
        _Float16* pa1 = (_Float16*)d_ws;
        _Float16* pb1 = pa1 + (size_t)n1 * 16;
        _Float16* pa2 = pb1 + (size_t)n1 * 16;
        _Float16* pb2 = pa2 + (size_t)n2 * 16;
        int prep_n = out_size > n1 ? out_size : n1;
        if (n2 > prep_n) prep_n = n2;
        prep_fp16<<<(prep_n + TPB - 1) / TPB, TPB, 0, stream>>>(
            xyz1, xyz2, pa1, pb1, pa2, pb2, out, n1, n2, out_size);

        const int grid = 2 * BATCH * (N / 256) * NJ;   // 2048
        chamfer_mfma32<NJ><<<grid, TPB, 0, stream>>>(pa1, pb1, pa2, pb2, out, N);
        return;
    }

    // fallback: R6 pk-fma path
    constexpr int CHUNK = 128;
    constexpr int P = 8;
    const size_t need = ((size_t)n1 + (size_t)n2) * sizeof(float4);
    if (ws_size >= need && (N % (TPB * P) == 0) && (M % (TPB * P) == 0) &&
        (N % CHUNK == 0) && (M % CHUNK == 0)) {
        float4* pk1 = (float4*)d_ws;
        float4* pk2 = pk1 + n1;
        int prep_n = out_size > n1 ? out_size : n1;
        if (n2 > prep_n) prep_n = n2;
        chamfer_prep<<<(prep_n + TPB - 1) / TPB, TPB, 0, stream>>>(
            xyz1, xyz2, pk1, pk2, out, n1, n2, out_size);
        const int blocks_dir0 = BATCH * (N / (TPB * P)) * (M / CHUNK);
        const int blocks_dir1 = BATCH * (M / (TPB * P)) * (N / CHUNK);
        chamfer_fused<TPB, CHUNK, P><<<blocks_dir0 + blocks_dir1, TPB, 0, stream>>>(
            xyz1, xyz2, pk1, pk2, out, N, M, blocks_dir0);
    }
}

// Round 14
// 35.289 us; speedup vs baseline: 1.7811x; 1.0867x over previous
//
#include <hip/hip_runtime.h>
#include <float.h>

#define BATCH 4

typedef _Float16 half8 __attribute__((ext_vector_type(8)));
typedef float f32x16 __attribute__((ext_vector_type(16)));
typedef float f32x2 __attribute__((ext_vector_type(2)));

// ================= MFMA path =================
// D[p,q] = |p|^2 + |q|^2 - 2 p.q  via K=13 fp16 slots (exact split):
//  A[p] = [hx,hy,hz, hx,hy,hz, ex,ey,ez, ps_h, ps_e, 1, 1, 0,0,0]
//  B[q] = [-2hx,-2hy,-2hz, -2ex,-2ey,-2ez, -2hx,-2hy,-2hz, 1, 1, qs_h, qs_e, 0,0,0]
// fp16*fp16 products exact in fp32 accumulator. Verified R7-R13 (absmax ~1e-3).
// A rows = dst (scan) points, B cols = src (owned) points.
//
// A-form arrays are stored PRE-SWIZZLED in LDS-fragment order so that a
// LINEAR global_load_lds copy yields R11's verified LDS layout:
//   uint4 slot of (point j, half h) = (j>>5)*64 + h*32 + (j&31)
// B-form arrays stay point-major (j*2 + h).

__global__ void prep_fp16(const float* __restrict__ x1, const float* __restrict__ x2,
                          _Float16* __restrict__ pa1, _Float16* __restrict__ pb1,
                          _Float16* __restrict__ pa2, _Float16* __restrict__ pb2,
                          float* __restrict__ out, int n1, int n2, int outn) {
    const int i = blockIdx.x * blockDim.x + threadIdx.x;
    const _Float16 one = (_Float16)1.0f, zro = (_Float16)0.0f;

    #pragma unroll
    for (int which = 0; which < 2; ++which) {
        const int n = which ? n2 : n1;
        if (i >= n) continue;
        const float* xp = (which ? x2 : x1) + 3 * (size_t)i;
        _Float16* pa = (which ? pa2 : pa1);
        _Float16* pb = (which ? pb2 : pb1) + 16 * (size_t)i;

        const float x = xp[0], y = xp[1], z = xp[2];
        const _Float16 hx = (_Float16)x, hy = (_Float16)y, hz = (_Float16)z;
        const _Float16 ex = (_Float16)(x - (float)hx);
        const _Float16 ey = (_Float16)(y - (float)hy);
        const _Float16 ez = (_Float16)(z - (float)hz);
        const float ps = fmaf(x, x, fmaf(y, y, z * z));
        const _Float16 ph = (_Float16)ps;
        const _Float16 pe = (_Float16)(ps - (float)ph);
        const _Float16 tx = (_Float16)(-2.0f * (float)hx);
        const _Float16 ty = (_Float16)(-2.0f * (float)hy);
        const _Float16 tz = (_Float16)(-2.0f * (float)hz);
        const _Float16 ux = (_Float16)(-2.0f * (float)ex);
        const _Float16 uy = (_Float16)(-2.0f * (float)ey);
        const _Float16 uz = (_Float16)(-2.0f * (float)ez);

        const half8 a0 = (half8){hx, hy, hz, hx, hy, hz, ex, ey};
        const half8 a1 = (half8){ez, ph, pe, one, one, zro, zro, zro};
        const half8 b0 = (half8){tx, ty, tz, ux, uy, uz, tx, ty};
        const half8 b1 = (half8){tz, one, one, ph, pe, zro, zro, zro};

        // A: swizzled slots (LDS-fragment order)
        const size_t slot0 = ((size_t)(i >> 5) << 6) + (size_t)(i & 31);
        *(half8*)(pa + slot0 * 8)        = a0;   // half h=0
        *(half8*)(pa + (slot0 + 32) * 8) = a1;   // half h=1
        // B: natural point-major
        *(half8*)(pb)     = b0;
        *(half8*)(pb + 8) = b1;
    }
    if (i < outn) out[i] = FLT_MAX;
}

// Fold 16 fresh distances + running min into one scalar: 8 v_min3-class ops.
__device__ inline float min16_into(float r, const f32x16 d) {
    const float t0 = fminf(fminf(d[0],  d[1]),  d[2]);
    const float t1 = fminf(fminf(d[3],  d[4]),  d[5]);
    const float t2 = fminf(fminf(d[6],  d[7]),  d[8]);
    const float t3 = fminf(fminf(d[9],  d[10]), d[11]);
    const float t4 = fminf(fminf(d[12], d[13]), d[14]);
    const float u0 = fminf(fminf(t0, t1), t2);
    const float u1 = fminf(fminf(t3, t4), d[15]);
    return fminf(fminf(r, u0), u1);
}

// R14: double-buffered LDS staging via ASYNC global_load_lds (zero staging
// VGPRs — R12/R13 showed register pipelining crosses the 128-VGPR cliff).
// Stage s+1's loads are issued before stage s's compute; __syncthreads()
// (vmcnt(0)+barrier) per stage lands after ~380cyc of compute -> latency
// hidden. A-arrays are pre-swizzled so the linear DMA reproduces R11's
// verified conflict-free LDS layout bit-for-bit.
// NOTE: plain __launch_bounds__(256) — R5/R9: min-waves args spill f32x16.
// Layouts (verified R8/R10/R11):
//  A/B frag: row/col = lane&31, k-half = lane>>5 (8 contiguous f16 = 16B)
//  D: col = lane&31 (src i), row = (e&3)+8*(e>>2)+4*(lane>>5) (dst j)
template<int NJ>
__global__ __launch_bounds__(256) void chamfer_mfma32(
        const _Float16* __restrict__ pa1, const _Float16* __restrict__ pb1,
        const _Float16* __restrict__ pa2, const _Float16* __restrict__ pb2,
        float* __restrict__ out, int N) {
    constexpr int IT = 2;
    __shared__ uint4 sA[2][512];   // 2 x 8 KiB

    const int tid  = threadIdx.x;
    const int lane = tid & 63;
    const int w    = tid >> 6;

    int bid = blockIdx.x;
    const int RB      = N / 256;
    const int per_dir = BATCH * RB * NJ;
    const int dir = bid / per_dir;   bid %= per_dir;
    const int b   = bid / (RB * NJ); bid %= (RB * NJ);
    const int cb  = bid / NJ;        // src col-block
    const int js  = bid % NJ;        // dst segment

    // dir0: src=set1 (held B-form), scan dst=set2 (staged A-form)
    const _Float16* pstage = dir ? pa1 : pa2;
    const _Float16* pheld  = dir ? pb2 : pb1;
    float* outd = out + (size_t)dir * BATCH * N + (size_t)b * N;

    const int jseg   = N / NJ;
    const int stages = jseg / 256;
    const char* gbytes = (const char*)pstage;
    // segment byte base: swizzled A keeps points block-linear, 32B/point
    const size_t segbyte = ((size_t)b * N + (size_t)js * jseg) * 32;

    // ---- async stage issue: wave w copies bytes [w*2048, w*2048+2048) ----
    #define ISSUE_STAGE(s_, nxt_)                                              \
        do {                                                                   \
            const char* g0 = gbytes + segbyte + (size_t)(s_) * 8192            \
                           + (size_t)w * 2048 + (size_t)lane * 16;             \
            char* l0 = (char*)(&sA[(nxt_)][0]) + (size_t)w * 2048;             \
            __builtin_amdgcn_global_load_lds(                                  \
                (const __attribute__((address_space(1))) void*)g0,             \
                (__attribute__((address_space(3))) void*)l0, 16, 0, 0);        \
            __builtin_amdgcn_global_load_lds(                                  \
                (const __attribute__((address_space(1))) void*)(g0 + 1024),    \
                (__attribute__((address_space(3))) void*)(l0 + 1024), 16, 0, 0);\
        } while (0)

    // prologue: stage 0 into buf 0
    ISSUE_STAGE(0, 0);

    // Held src B-fragments: 16B per lane (completes before first barrier).
    const int colbase = cb * 256 + w * 64;
    const uint4* gh = (const uint4*)pheld;
    half8 bf[IT];
    #pragma unroll
    for (int it = 0; it < IT; ++it) {
        const int c = colbase + it * 32 + (lane & 31);
        bf[it] = __builtin_bit_cast(half8, gh[(size_t)(b * N + c) * 2 + (lane >> 5)]);
    }

    float rmin[IT];
    #pragma unroll
    for (int it = 0; it < IT; ++it) rmin[it] = FLT_MAX;

    f32x16 cz;
    #pragma unroll
    for (int e = 0; e < 16; ++e) cz[e] = 0.0f;

    __syncthreads();   // vmcnt(0) drain: stage 0 resident

    for (int s = 0; s < stages; ++s) {
        const int cur = s & 1;
        if (s + 1 < stages) ISSUE_STAGE(s + 1, cur ^ 1);  // async, no regs

        #pragma unroll 2
        for (int p = 0; p < 8; ++p) {
            const half8 a = __builtin_bit_cast(half8, sA[cur][p * 64 + lane]);
            #pragma unroll
            for (int it = 0; it < IT; ++it) {
                const f32x16 d = __builtin_amdgcn_mfma_f32_32x32x16_f16(a, bf[it], cz, 0, 0, 0);
                rmin[it] = min16_into(rmin[it], d);
            }
        }

        __syncthreads();   // drains vmcnt -> stage s+1 landed; one barrier/stage
    }
    #undef ISSUE_STAGE

    // epilogue: combine k-halves (lane L and L^32 hold complementary rows)
    #pragma unroll
    for (int it = 0; it < IT; ++it) {
        float v = fminf(rmin[it], __shfl_xor(rmin[it], 32, 64));
        v = fmaxf(v, 0.0f);              // >=0 keeps int-punned min ordering
        if (lane < 32)
            atomicMin((int*)&outd[colbase + it * 32 + lane], __float_as_int(v));
    }
}

// ================= fallback: R6 pk-fma path =================
__global__ void chamfer_prep(const float* __restrict__ xyz1,
                             const float* __restrict__ xyz2,
                             float4* __restrict__ pk1,
                             float4* __restrict__ pk2,
                             float* __restrict__ out,
                             int n1, int n2, int out_n) {
    int i = blockIdx.x * blockDim.x + threadIdx.x;
    if (i < n1) {
        float x = xyz1[3 * (size_t)i], y = xyz1[3 * (size_t)i + 1], z = xyz1[3 * (size_t)i + 2];
        pk1[i] = make_float4(-2.f * x, -2.f * y, -2.f * z, fmaf(x, x, fmaf(y, y, z * z)));
    }
    if (i < n2) {
        float x = xyz2[3 * (size_t)i], y = xyz2[3 * (size_t)i + 1], z = xyz2[3 * (size_t)i + 2];
        pk2[i] = make_float4(-2.f * x, -2.f * y, -2.f * z, fmaf(x, x, fmaf(y, y, z * z)));
    }
    if (i < out_n) out[i] = FLT_MAX;
}

template<int TPB, int CHUNK, int P>
__global__ __launch_bounds__(TPB) void chamfer_fused(
        const float* __restrict__ xyz1, const float* __restrict__ xyz2,
        const float4* __restrict__ pk1, const float4* __restrict__ pk2,
        float* __restrict__ out, int N, int M, int blocks_dir0) {
    __shared__ float4 s[CHUNK];
    int bid = blockIdx.x;
    const int dir = (bid >= blocks_dir0) ? 1 : 0;
    if (dir) bid -= blocks_dir0;
    const int Nsrc = dir ? M : N;
    const int Mdst = dir ? N : M;
    const float* src   = dir ? xyz2 : xyz1;
    const float4* dstp = dir ? pk1  : pk2;
    float* outd        = dir ? (out + (size_t)BATCH * N) : out;
    const int YT = Nsrc / (TPB * P);
    const int Z  = Mdst / CHUNK;
    const int b  = bid / (YT * Z);
    const int r  = bid % (YT * Z);
    const int yt = r / Z;
    const int z  = r % Z;
    const float4* dchunk = dstp + (size_t)b * Mdst + (size_t)z * CHUNK;
    for (int t = threadIdx.x; t < CHUNK / 2; t += TPB) {
        const float4 q0 = dchunk[2 * t];
        const float4 q1 = dchunk[2 * t + 1];
        s[2 * t]     = make_float4(q0.x, q1.x, q0.y, q1.y);
        s[2 * t + 1] = make_float4(q0.z, q1.z, q0.w, q1.w);
    }
    const int i0 = yt * (TPB * P) + threadIdx.x;
    f32x2 px[P], py[P], pz[P];
    float psq[P], m[P];
    #pragma unroll
    for (int k = 0; k < P; ++k) {
        const int i = i0 + k * TPB;
        const float* p = src + ((size_t)b * Nsrc + i) * 3;
        const float x = p[0], y = p[1], zc = p[2];
        px[k] = (f32x2){x, x}; py[k] = (f32x2){y, y}; pz[k] = (f32x2){zc, zc};
        psq[k] = fmaf(x, x, fmaf(y, y, zc * zc));
        m[k] = FLT_MAX;
    }
    __syncthreads();
    #pragma unroll 8
    for (int jj = 0; jj < CHUNK / 2; ++jj) {
        const float4 A = s[2 * jj];
        const float4 B = s[2 * jj + 1];
        const f32x2 xq = (f32x2){A.x, A.y};
        const f32x2 yq = (f32x2){A.z, A.w};
        const f32x2 zq = (f32x2){B.x, B.y};
        const f32x2 wq = (f32x2){B.z, B.w};
        #pragma unroll
        for (int k = 0; k < P; ++k) {
            const f32x2 e = __builtin_elementwise_fma(xq, px[k],
                             __builtin_elementwise_fma(yq, py[k],
                              __builtin_elementwise_fma(zq, pz[k], wq)));
            m[k] = fminf(fminf(m[k], e.x), e.y);
        }
    }
    #pragma unroll
    for (int k = 0; k < P; ++k) {
        const int i = i0 + k * TPB;
        const float d = fmaxf(psq[k] + m[k], 0.0f);
        atomicMin((int*)&outd[(size_t)b * Nsrc + i], __float_as_int(d));
    }
}

extern "C" void kernel_launch(void* const* d_in, const int* in_sizes, int n_in,
                              void* d_out, int out_size, void* d_ws, size_t ws_size,
                              hipStream_t stream) {
    const float* xyz1 = (const float*)d_in[0];
    const float* xyz2 = (const float*)d_in[1];
    float* out = (float*)d_out;

    const int N = in_sizes[0] / (BATCH * 3);  // 8192
    const int M = in_sizes[1] / (BATCH * 3);  // 8192
    const int n1 = BATCH * N, n2 = BATCH * M;

    constexpr int TPB = 256;
    constexpr int NJ = 8;

    const size_t need16 = ((size_t)n1 + (size_t)n2) * 64;  // A+B fp16 forms
    const bool mfma_ok = (N == M) && (N % (NJ * 256) == 0) && (ws_size >= need16);

    if (mfma_ok) {
        _Float16* pa1 = (_Float16*)d_ws;
        _Float16* pb1 = pa1 + (size_t)n1 * 16;
        _Float16* pa2 = pb1 + (size_t)n1 * 16;
        _Float16* pb2 = pa2 + (size_t)n2 * 16;
        int prep_n = out_size > n1 ? out_size : n1;
        if (n2 > prep_n) prep_n = n2;
        prep_fp16<<<(prep_n + TPB - 1) / TPB, TPB, 0, stream>>>(
            xyz1, xyz2, pa1, pb1, pa2, pb2, out, n1, n2, out_size);

        const int grid = 2 * BATCH * (N / 256) * NJ;   // 2048
        chamfer_mfma32<NJ><<<grid, TPB, 0, stream>>>(pa1, pb1, pa2, pb2, out, N);
        return;
    }

    // fallback: R6 pk-fma path
    constexpr int CHUNK = 128;
    constexpr int P = 8;
    const size_t need = ((size_t)n1 + (size_t)n2) * sizeof(float4);
    if (ws_size >= need && (N % (TPB * P) == 0) && (M % (TPB * P) == 0) &&
        (N % CHUNK == 0) && (M % CHUNK == 0)) {
        float4* pk1 = (float4*)d_ws;
        float4* pk2 = pk1 + n1;
        int prep_n = out_size > n1 ? out_size : n1;
        if (n2 > prep_n) prep_n = n2;
        chamfer_prep<<<(prep_n + TPB - 1) / TPB, TPB, 0, stream>>>(
            xyz1, xyz2, pk1, pk2, out, n1, n2, out_size);
        const int blocks_dir0 = BATCH * (N / (TPB * P)) * (M / CHUNK);
        const int blocks_dir1 = BATCH * (M / (TPB * P)) * (N / CHUNK);
        chamfer_fused<TPB, CHUNK, P><<<blocks_dir0 + blocks_dir1, TPB, 0, stream>>>(
            xyz1, xyz2, pk1, pk2, out, N, M, blocks_dir0);
    }
}